// Round 12
// baseline (82.124 us; speedup 1.0000x reference)
//
#include <hip/hip_runtime.h>
#include <math.h>

#pragma clang fp contract(off)

constexpr int NB  = 16;    // batch
constexpr int NR  = 4096;  // rois per image
constexpr int NC  = 81;    // classes (incl. background)
constexpr int NCM1 = NC - 1;              // foreground classes
constexpr int KK  = 200;   // per-class candidate cap == max_total
constexpr int CAP = 4096;  // max kept entries per image (<= NR)
constexpr int MAXC = 1024;                // per-class LDS candidate cap
constexpr int TCHUNK = 256;
constexpr int NCHUNK = CAP / TCHUNK;      // 16 blocks per image
constexpr float SCORE_TH = 0.5f;
constexpr float IOU_TH   = 0.5f;
constexpr float EPSF     = 1e-8f;

struct SK { float s; int key; };   // 8B packed (score, cls*KK + prenms_rank)

// One block per (image, fg-class). Softmax fact: candidate <=> p[r,c] > 0.5
// (p>0.5 forces argmax==c; background can never exceed 0.5 when a fg class
// does). Scan column c -> LDS list -> stable rank -> decode top-200 only ->
// mask-NMS -> compact into fixed (b,c) segment. kcnt written unconditionally
// every call: no init pass, no global atomics anywhere.
__global__ void k_perclass(const float* __restrict__ probs,
                           const float* __restrict__ roi,
                           const float* __restrict__ deltas,
                           int* __restrict__ kcnt,
                           SK* __restrict__ sk_seg,
                           float4* __restrict__ fbox_seg) {
    __shared__ int   lcnt;
    __shared__ float ls[MAXC], lroi[MAXC];
    __shared__ float ss[KK], sy1[KK], sx1[KK], sy2[KK], sx2[KK], sar[KK];
    __shared__ unsigned long long sup[KK][4];
    __shared__ int   skeep[KK];

    const int bid = blockIdx.x, tid = threadIdx.x;
    const int b = bid / NCM1, cm1 = bid % NCM1, c = cm1 + 1;

    if (tid == 0) lcnt = 0;
    __syncthreads();

    // strided column scan (L3-resident; ~64 lines per wave-load)
    const float* pcol = probs + (size_t)b * NR * NC + c;
    #pragma unroll 4
    for (int r = tid; r < NR; r += 256) {
        float p = pcol[(size_t)r * NC];
        if (p > SCORE_TH) {
            int q = atomicAdd(&lcnt, 1);          // LDS atomic; order-free keys
            if (q < MAXC) { ls[q] = p; lroi[q] = (float)r; }
        }
    }
    __syncthreads();

    int Mc = lcnt < MAXC ? lcnt : MAXC;
    if (Mc == 0) {
        if (tid == 0) kcnt[b * NCM1 + cm1] = 0;
        return;
    }

    // stable rank by (score desc, roi asc) — lax.top_k order; decode survivors
    for (int i = tid; i < Mc; i += 256) {
        float si = ls[i], ri = lroi[i];
        int rank = 0;
        for (int j = 0; j < Mc; ++j) {
            float sj = ls[j], rj = lroi[j];
            rank += (int)((sj > si) | ((sj == si) & (rj < ri)));
        }
        if (rank < KK) {
            int r = (int)ri;
            float4 a = ((const float4*)roi)[(size_t)b * NR + r];
            float4 d = *(const float4*)(deltas + (((size_t)b * NR + r) * NC + c) * 4);
            float ah  = a.z - a.x;
            float aw  = a.w - a.y;
            float acy = a.x + 0.5f * ah;
            float acx = a.y + 0.5f * aw;
            float dy = d.x * 0.1f, dx = d.y * 0.1f;
            float dh = d.z * 0.2f, dw = d.w * 0.2f;
            float bh  = expf(dh) * ah;
            float bw  = expf(dw) * aw;
            float bcy = dy * ah + acy;
            float bcx = dx * aw + acx;
            float y1 = bcy - 0.5f * bh;
            float x1 = bcx - 0.5f * bw;
            float y2 = y1 + bh;
            float x2 = x1 + bw;
            ss[rank] = si;
            sy1[rank] = y1; sx1[rank] = x1; sy2[rank] = y2; sx2[rank] = x2;
            sar[rank] = fmaxf(y2 - y1, 0.f) * fmaxf(x2 - x1, 0.f);
        }
    }
    __syncthreads();

    int L = Mc < KK ? Mc : KK;

    // parallel suppression-mask build: sup[i] = {j>i : IoU(i,j) > TH}
    for (int idx = tid; idx < L * 4; idx += 256) {
        int i = idx >> 2, w = idx & 3;
        int j0 = w * 64;
        unsigned long long bits = 0;
        int jend = j0 + 64 < L ? j0 + 64 : L;
        int jstart = j0 > i + 1 ? j0 : i + 1;
        if (jstart < jend) {
            float yi1 = sy1[i], xi1 = sx1[i], yi2 = sy2[i], xi2 = sx2[i], ai = sar[i];
            for (int j = jstart; j < jend; ++j) {
                float yy1 = fmaxf(yi1, sy1[j]), xx1 = fmaxf(xi1, sx1[j]);
                float yy2 = fminf(yi2, sy2[j]), xx2 = fminf(xi2, sx2[j]);
                float inter = fmaxf(yy2 - yy1, 0.f) * fmaxf(xx2 - xx1, 0.f);
                float uni = ai + sar[j] - inter;
                if (inter / (uni + EPSF) > IOU_TH) bits |= 1ull << (j - j0);
            }
        }
        sup[i][w] = bits;
    }
    __syncthreads();

    // greedy scan on wave 0: keep-bits in registers (4 bits/lane)
    if (tid < 64) {
        int lane = tid;
        int kmask = 0;
        #pragma unroll
        for (int s = 0; s < 4; ++s) if (s * 64 + lane < L) kmask |= 1 << s;
        for (int i = 0; i < L; ++i) {
            int oi = i & 63, si = i >> 6;
            unsigned long long r0 = sup[i][0], r1 = sup[i][1];
            unsigned long long r2 = sup[i][2], r3 = sup[i][3];
            int keep_i = (__shfl(kmask, oi) >> si) & 1;   // uniform across wave
            if (keep_i) {
                int supb = (int)((r0 >> lane) & 1)
                         | ((int)((r1 >> lane) & 1) << 1)
                         | ((int)((r2 >> lane) & 1) << 2)
                         | ((int)((r3 >> lane) & 1) << 3);
                kmask &= ~supb;
            }
        }
        #pragma unroll
        for (int s = 0; s < 4; ++s) {
            int jj = s * 64 + lane;
            if (jj < L) skeep[jj] = (kmask >> s) & 1;
        }
    }
    __syncthreads();

    // compact kept entries into the fixed (b,c) segment (no atomics)
    for (int i = tid; i < L; i += 256) {
        if (skeep[i]) {
            int pos = 0;
            for (int j = 0; j < i; ++j) pos += skeep[j];
            size_t idx = ((size_t)b * NC + c) * KK + pos;
            sk_seg[idx].s = ss[i];
            sk_seg[idx].key = c * KK + i;
            fbox_seg[idx] = make_float4(sy1[i], sx1[i], sy2[i], sx2[i]);
        }
    }
    if (tid == 0) {
        int tot = 0;
        for (int i = 0; i < L; ++i) tot += skeep[i];
        kcnt[b * NCM1 + cm1] = tot;
    }
}

// NCHUNK blocks per image: prefix over 80 class counts -> gather compact
// (score,key) list into LDS (binary-search segment lookup) -> each thread
// ranks ONE entry (float4 = 2 entries/read) -> direct scatter write (ranks
// unique & dense). Box fetched by key: seg index = b*NC*KK + key.
__global__ void k_topk(const int* __restrict__ kcnt,
                       const SK* __restrict__ sk_seg,
                       const float4* __restrict__ fbox_seg,
                       float* __restrict__ out) {
    int b = blockIdx.x / NCHUNK, chunk = blockIdx.x % NCHUNK;
    const int tid = threadIdx.x;

    __shared__ int pfx[NCM1 + 1];
    __shared__ SK  sL[CAP];   // 32 KB packed (score,key)

    if (tid < NCM1) pfx[tid + 1] = kcnt[b * NCM1 + tid];
    if (tid == 0) pfx[0] = 0;
    __syncthreads();
    if (tid == 0) {
        int run = 0;
        for (int s = 1; s <= NCM1; ++s) { run += pfx[s]; pfx[s] = run; }
    }
    __syncthreads();
    int M = pfx[NCM1];

    float* obox = out + (size_t)b * KK * 4;
    float* olbl = out + (size_t)NB * KK * 4 + (size_t)b * KK;
    float* osc  = out + (size_t)NB * KK * 5 + (size_t)b * KK;

    if (chunk == 0) {   // zero the unwritten tail every call (deterministic output)
        int Mi = M < KK ? M : KK;
        for (int i = Mi + tid; i < KK; i += 256) {
            obox[i * 4 + 0] = 0.f; obox[i * 4 + 1] = 0.f;
            obox[i * 4 + 2] = 0.f; obox[i * 4 + 3] = 0.f;
            olbl[i] = 0.f; osc[i] = 0.f;
        }
    }
    if (chunk * TCHUNK >= M) return;

    // gather compact list: binary search segment for each compact index
    for (int i = tid; i < M; i += 256) {
        int lo = 0, hi = NCM1;            // find s: pfx[s] <= i < pfx[s+1]
        while (lo + 1 < hi + 1) {         // invariant: pfx[lo] <= i
            int mid = (lo + hi + 1) >> 1;
            if (pfx[mid] <= i) lo = mid; else hi = mid - 1;
        }
        int cseg = lo + 1;                // class
        int k = i - pfx[lo];
        sL[i] = sk_seg[((size_t)b * NC + cseg) * KK + k];
    }
    __syncthreads();

    int e = chunk * TCHUNK + tid;
    if (e >= M) return;
    float se = sL[e].s; int ke = sL[e].key;
    int rank = 0;
    const float4* p4 = (const float4*)sL;   // 2 SK per float4
    int npair = M >> 1;
    #pragma unroll 4
    for (int p = 0; p < npair; ++p) {
        float4 v = p4[p];
        int k0 = __float_as_int(v.y), k1 = __float_as_int(v.w);
        rank += (int)((v.x > se) | ((v.x == se) & (k0 < ke)));
        rank += (int)((v.z > se) | ((v.z == se) & (k1 < ke)));
    }
    if (M & 1) {
        float sj = sL[M - 1].s; int kj = sL[M - 1].key;
        rank += (int)((sj > se) | ((sj == se) & (kj < ke)));
    }
    if (rank < KK) {
        float4 bx = fbox_seg[(size_t)b * NC * KK + ke];
        obox[rank * 4 + 0] = fminf(fmaxf(bx.x, 0.f), 1.f);
        obox[rank * 4 + 1] = fminf(fmaxf(bx.y, 0.f), 1.f);
        obox[rank * 4 + 2] = fminf(fmaxf(bx.z, 0.f), 1.f);
        obox[rank * 4 + 3] = fminf(fmaxf(bx.w, 0.f), 1.f);
        olbl[rank] = (float)(ke / KK);
        osc[rank]  = se;
    }
}

extern "C" void kernel_launch(void* const* d_in, const int* in_sizes, int n_in,
                              void* d_out, int out_size, void* d_ws, size_t ws_size,
                              hipStream_t stream) {
    const float* roi    = (const float*)d_in[0];
    const float* deltas = (const float*)d_in[1];
    const float* probs  = (const float*)d_in[2];
    float* out = (float*)d_out;

    char* base = (char*)d_ws;
    int*    kcnt     = (int*)base;                                   // 16*80 ints
    SK*     sk_seg   = (SK*)(base + 8192);                           // 16*81*200*8  = 2.07 MB
    float4* fbox_seg = (float4*)(base + 8192 + 2073600);             // 16*81*200*16 = 4.15 MB

    k_perclass<<<NB * NCM1, 256, 0, stream>>>(probs, roi, deltas,
                                              kcnt, sk_seg, fbox_seg);
    k_topk<<<NB * NCHUNK, 256, 0, stream>>>(kcnt, sk_seg, fbox_seg, out);
}

// Round 13
// 69.225 us; speedup vs baseline: 1.1863x; 1.1863x over previous
//
#include <hip/hip_runtime.h>
#include <math.h>

#pragma clang fp contract(off)

constexpr int NB  = 16;    // batch
constexpr int NR  = 4096;  // rois per image
constexpr int NC  = 81;    // classes (incl. background)
constexpr int NCM1 = NC - 1;              // foreground classes
constexpr int KK  = 200;   // per-class candidate cap == max_total
constexpr int CAP = 4096;  // max kept entries per image
constexpr int ROWS_PER_BLK = 64;
constexpr int CHUNKS = NR / ROWS_PER_BLK;     // 64 chunks per image
constexpr int GRID = NB * NR / ROWS_PER_BLK;  // 1024 blocks
constexpr int MAXC = 1024;                    // per-class LDS candidate cap
constexpr int TCHUNK = 256;
constexpr int NCHUNK = CAP / TCHUNK;          // 16 blocks per image
constexpr float SCORE_TH = 0.5f;
constexpr float IOU_TH   = 0.5f;
constexpr float EPSF     = 1e-8f;

struct SK { float s; int key; };   // 8B packed (score, cls*KK + prenms_rank)

__device__ __forceinline__ void decode_box(const float4& a, const float4& d,
                                           float& y1, float& x1, float& y2, float& x2) {
    float ah  = a.z - a.x;
    float aw  = a.w - a.y;
    float acy = a.x + 0.5f * ah;
    float acx = a.y + 0.5f * aw;
    float dy = d.x * 0.1f, dx = d.y * 0.1f;
    float dh = d.z * 0.2f, dw = d.w * 0.2f;
    float bh  = expf(dh) * ah;
    float bw  = expf(dw) * aw;
    float bcy = dy * ah + acy;
    float bcx = dx * aw + acx;
    y1 = bcy - 0.5f * bh;
    x1 = bcx - 0.5f * bw;
    y2 = y1 + bh;
    x2 = x1 + bw;
}

// 4 threads/ROI, 64 ROIs/block. Ballot-compaction into per-block fixed slots:
// blk_cnt[bid] written unconditionally -> no init kernel, no global atomics.
__global__ void k_classify(const float* __restrict__ roi,
                           const float* __restrict__ deltas,
                           const float* __restrict__ probs,
                           int* __restrict__ blk_cnt,
                           int* __restrict__ scls,
                           float2* __restrict__ ssr,
                           float4* __restrict__ sbox) {
    __shared__ float lp[ROWS_PER_BLK * NC];   // 20736 B
    __shared__ int wcnt[4], wbase[4];
    const int bid = blockIdx.x, tid = threadIdx.x;

    const float4* src = (const float4*)(probs + (size_t)bid * ROWS_PER_BLK * NC);
    float4* dst = (float4*)lp;
    for (int v = tid; v < ROWS_PER_BLK * NC / 4; v += 256) dst[v] = src[v];
    __syncthreads();

    int g = tid >> 2;               // row within block
    int j = tid & 3;                // sub-lane within row group
    const float* row = lp + g * NC;
    float m = -1.0f;
    int am = 127;
    for (int c = j; c < NC; c += 4) {
        float v = row[c];
        if (v > m) { m = v; am = c; }            // first-max within subset
    }
    for (int mask = 1; mask <= 2; mask <<= 1) {  // butterfly: all 4 get result
        float om = __shfl_xor(m, mask);
        int   oi = __shfl_xor(am, mask);
        if (om > m || (om == m && oi < am)) { m = om; am = oi; }
    }

    bool pred = (j == 0) && (am != 0) && (m > SCORE_TH);
    unsigned long long bal = __ballot(pred);
    int lane = tid & 63, w = tid >> 6;
    if (lane == 0) wcnt[w] = __popcll(bal);
    __syncthreads();
    if (tid == 0) {
        int run = 0;
        for (int i = 0; i < 4; ++i) { wbase[i] = run; run += wcnt[i]; }
        blk_cnt[bid] = run;
    }
    __syncthreads();

    if (pred) {
        int pos = wbase[w] + __popcll(bal & ((1ull << lane) - 1ull));
        int r = bid * ROWS_PER_BLK + g;
        float4 a = ((const float4*)roi)[r];
        float4 d = *(const float4*)(deltas + ((size_t)r * NC + am) * 4);
        float y1, x1, y2, x2;
        decode_box(a, d, y1, x1, y2, x2);
        int idx = bid * ROWS_PER_BLK + pos;      // == b*NR + chunk*64 + pos
        scls[idx] = am;
        ssr[idx]  = make_float2(m, (float)(r & (NR - 1)));   // exact: r%NR < 2^24
        sbox[idx] = make_float4(y1, x1, y2, x2);
    }
}

// One block per (image, fg-class): gather class-c candidates via scls scan ->
// LDS stable rank -> top-200 -> parallel mask build -> wave-0 greedy NMS ->
// write to fixed (b,c) segment. sk_seg compacted at post-NMS pos; fbox_seg at
// PRE-NMS rank i (k_topk fetches boxes by key = c*KK+i). kcnt written
// unconditionally -> no init pass, no global atomics.
__global__ void k_perclass(const int* __restrict__ blk_cnt,
                           const int* __restrict__ scls,
                           const float2* __restrict__ ssr,
                           const float4* __restrict__ sbox,
                           int* __restrict__ kcnt,
                           SK* __restrict__ sk_seg,
                           float4* __restrict__ fbox_seg) {
    __shared__ int ccnt[CHUNKS];
    __shared__ int lcnt;
    __shared__ float ls[MAXC], lroi[MAXC];
    __shared__ unsigned short lidx[MAXC];
    __shared__ float ss[KK], sy1[KK], sx1[KK], sy2[KK], sx2[KK], sar[KK];
    __shared__ unsigned long long sup[KK][4];
    __shared__ int skeep[KK];

    const int bid = blockIdx.x, tid = threadIdx.x;
    const int b = bid / NCM1, cm1 = bid % NCM1, c = cm1 + 1;

    if (tid < CHUNKS) ccnt[tid] = blk_cnt[b * CHUNKS + tid];
    if (tid == 0) lcnt = 0;
    __syncthreads();

    const int* sc = scls + (size_t)b * NR;
    const float2* sr = ssr + (size_t)b * NR;
    for (int sidx = tid; sidx < NR; sidx += 256) {
        int chunk = sidx >> 6, s = sidx & 63;
        if (s < ccnt[chunk] && sc[sidx] == c) {
            int p = atomicAdd(&lcnt, 1);         // LDS atomic; order-free keys
            if (p < MAXC) {
                float2 v = sr[sidx];
                ls[p] = v.x; lroi[p] = v.y; lidx[p] = (unsigned short)sidx;
            }
        }
    }
    __syncthreads();
    int Mc = lcnt < MAXC ? lcnt : MAXC;
    if (Mc == 0) {
        if (tid == 0) kcnt[bid] = 0;
        return;
    }

    // stable rank by (score desc, roi asc) — lax.top_k order
    for (int i = tid; i < Mc; i += 256) {
        float si = ls[i], ri = lroi[i];
        int rank = 0;
        for (int jj = 0; jj < Mc; ++jj) {
            float sj = ls[jj], rj = lroi[jj];
            rank += (int)((sj > si) | ((sj == si) & (rj < ri)));
        }
        if (rank < KK) {
            float4 bx = sbox[(size_t)b * NR + lidx[i]];
            ss[rank] = si;
            sy1[rank] = bx.x; sx1[rank] = bx.y; sy2[rank] = bx.z; sx2[rank] = bx.w;
            sar[rank] = fmaxf(bx.z - bx.x, 0.f) * fmaxf(bx.w - bx.y, 0.f);
        }
    }
    __syncthreads();

    int L = Mc < KK ? Mc : KK;

    // parallel suppression-mask build: sup[i] = {j>i : IoU(i,j) > TH}
    for (int idx = tid; idx < L * 4; idx += 256) {
        int i = idx >> 2, w = idx & 3;
        int j0 = w * 64;
        unsigned long long bits = 0;
        int jend = j0 + 64 < L ? j0 + 64 : L;
        int jstart = j0 > i + 1 ? j0 : i + 1;
        if (jstart < jend) {
            float yi1 = sy1[i], xi1 = sx1[i], yi2 = sy2[i], xi2 = sx2[i], ai = sar[i];
            for (int j = jstart; j < jend; ++j) {
                float yy1 = fmaxf(yi1, sy1[j]), xx1 = fmaxf(xi1, sx1[j]);
                float yy2 = fminf(yi2, sy2[j]), xx2 = fminf(xi2, sx2[j]);
                float inter = fmaxf(yy2 - yy1, 0.f) * fmaxf(xx2 - xx1, 0.f);
                float uni = ai + sar[j] - inter;
                if (inter / (uni + EPSF) > IOU_TH) bits |= 1ull << (j - j0);
            }
        }
        sup[i][w] = bits;
    }
    __syncthreads();

    // greedy scan on wave 0: keep-bits in registers (4 bits/lane)
    if (tid < 64) {
        int lane = tid;
        int kmask = 0;
        #pragma unroll
        for (int s = 0; s < 4; ++s) if (s * 64 + lane < L) kmask |= 1 << s;
        for (int i = 0; i < L; ++i) {
            int oi = i & 63, si = i >> 6;
            unsigned long long r0 = sup[i][0], r1 = sup[i][1];
            unsigned long long r2 = sup[i][2], r3 = sup[i][3];
            int keep_i = (__shfl(kmask, oi) >> si) & 1;   // uniform across wave
            if (keep_i) {
                int supb = (int)((r0 >> lane) & 1)
                         | ((int)((r1 >> lane) & 1) << 1)
                         | ((int)((r2 >> lane) & 1) << 2)
                         | ((int)((r3 >> lane) & 1) << 3);
                kmask &= ~supb;
            }
        }
        #pragma unroll
        for (int s = 0; s < 4; ++s) {
            int jj = s * 64 + lane;
            if (jj < L) skeep[jj] = (kmask >> s) & 1;
        }
    }
    __syncthreads();

    // write kept: sk compacted at pos; fbox at PRE-NMS rank i (key-addressable)
    for (int i = tid; i < L; i += 256) {
        if (skeep[i]) {
            int pos = 0;
            for (int j = 0; j < i; ++j) pos += skeep[j];
            size_t segbase = (size_t)bid * KK;
            sk_seg[segbase + pos].s = ss[i];
            sk_seg[segbase + pos].key = c * KK + i;
            fbox_seg[segbase + i] = make_float4(sy1[i], sx1[i], sy2[i], sx2[i]);
        }
    }
    if (tid == 0) {
        int tot = 0;
        for (int i = 0; i < L; ++i) tot += skeep[i];
        kcnt[bid] = tot;
    }
}

// NCHUNK blocks per image: prefix over 80 class counts -> gather compact
// (score,key) list into LDS (binary-search segment lookup) -> each thread
// ranks ONE entry (float4 = 2 entries/read) -> direct scatter write (ranks
// unique & dense). Box fetched by key: fg class cm1 = ke/KK - 1, i = ke%KK.
__global__ void k_topk(const int* __restrict__ kcnt,
                       const SK* __restrict__ sk_seg,
                       const float4* __restrict__ fbox_seg,
                       float* __restrict__ out) {
    int b = blockIdx.x / NCHUNK, chunk = blockIdx.x % NCHUNK;
    const int tid = threadIdx.x;

    __shared__ int pfx[NCM1 + 1];
    __shared__ SK  sL[CAP];   // 32 KB packed (score,key)

    if (tid < NCM1) pfx[tid + 1] = kcnt[b * NCM1 + tid];
    if (tid == 0) pfx[0] = 0;
    __syncthreads();
    if (tid == 0) {
        int run = 0;
        for (int s = 1; s <= NCM1; ++s) { run += pfx[s]; pfx[s] = run; }
    }
    __syncthreads();
    int M = pfx[NCM1];

    float* obox = out + (size_t)b * KK * 4;
    float* olbl = out + (size_t)NB * KK * 4 + (size_t)b * KK;
    float* osc  = out + (size_t)NB * KK * 5 + (size_t)b * KK;

    if (chunk == 0) {   // zero the unwritten tail every call (deterministic output)
        int Mi = M < KK ? M : KK;
        for (int i = Mi + tid; i < KK; i += 256) {
            obox[i * 4 + 0] = 0.f; obox[i * 4 + 1] = 0.f;
            obox[i * 4 + 2] = 0.f; obox[i * 4 + 3] = 0.f;
            olbl[i] = 0.f; osc[i] = 0.f;
        }
    }
    if (chunk * TCHUNK >= M) return;

    // gather compact list: binary search segment for each compact index
    for (int i = tid; i < M; i += 256) {
        int lo = 0, hi = NCM1 - 1;        // find lo: pfx[lo] <= i < pfx[lo+1]
        while (lo < hi) {
            int mid = (lo + hi + 1) >> 1;
            if (pfx[mid] <= i) lo = mid; else hi = mid - 1;
        }
        int k = i - pfx[lo];
        sL[i] = sk_seg[((size_t)b * NCM1 + lo) * KK + k];
    }
    __syncthreads();

    int e = chunk * TCHUNK + tid;
    if (e >= M) return;
    float se = sL[e].s; int ke = sL[e].key;
    int rank = 0;
    const float4* p4 = (const float4*)sL;   // 2 SK per float4
    int npair = M >> 1;
    #pragma unroll 4
    for (int p = 0; p < npair; ++p) {
        float4 v = p4[p];
        int k0 = __float_as_int(v.y), k1 = __float_as_int(v.w);
        rank += (int)((v.x > se) | ((v.x == se) & (k0 < ke)));
        rank += (int)((v.z > se) | ((v.z == se) & (k1 < ke)));
    }
    if (M & 1) {
        float sj = sL[M - 1].s; int kj = sL[M - 1].key;
        rank += (int)((sj > se) | ((sj == se) & (kj < ke)));
    }
    if (rank < KK) {
        int cm1 = ke / KK - 1, ipre = ke % KK;
        float4 bx = fbox_seg[((size_t)b * NCM1 + cm1) * KK + ipre];
        obox[rank * 4 + 0] = fminf(fmaxf(bx.x, 0.f), 1.f);
        obox[rank * 4 + 1] = fminf(fmaxf(bx.y, 0.f), 1.f);
        obox[rank * 4 + 2] = fminf(fmaxf(bx.z, 0.f), 1.f);
        obox[rank * 4 + 3] = fminf(fmaxf(bx.w, 0.f), 1.f);
        olbl[rank] = (float)(ke / KK);
        osc[rank]  = se;
    }
}

extern "C" void kernel_launch(void* const* d_in, const int* in_sizes, int n_in,
                              void* d_out, int out_size, void* d_ws, size_t ws_size,
                              hipStream_t stream) {
    const float* roi    = (const float*)d_in[0];
    const float* deltas = (const float*)d_in[1];
    const float* probs  = (const float*)d_in[2];
    float* out = (float*)d_out;

    char* base = (char*)d_ws;
    int*    blk_cnt  = (int*)base;                               // 4 KB
    int*    kcnt     = (int*)(base + 4096);                      // 16*80 ints = 5 KB
    int*    scls     = (int*)(base + 16384);                     // 256 KB
    float2* ssr      = (float2*)(base + 16384 + 262144);         // 512 KB
    float4* sbox     = (float4*)(base + 16384 + 262144 + 524288);               // 1 MB
    SK*     sk_seg   = (SK*)(base + 16384 + 262144 + 524288 + 1048576);         // 2.05 MB
    float4* fbox_seg = (float4*)(base + 16384 + 262144 + 524288 + 1048576 + 2097152); // 4.1 MB

    k_classify<<<GRID, 256, 0, stream>>>(roi, deltas, probs, blk_cnt,
                                         scls, ssr, sbox);
    k_perclass<<<NB * NCM1, 256, 0, stream>>>(blk_cnt, scls, ssr, sbox,
                                              kcnt, sk_seg, fbox_seg);
    k_topk<<<NB * NCHUNK, 256, 0, stream>>>(kcnt, sk_seg, fbox_seg, out);
}